// Round 22
// baseline (424.610 us; speedup 1.0000x reference)
//
#include <hip/hip_runtime.h>

typedef unsigned short u16;
typedef __attribute__((ext_vector_type(8))) __bf16 bf16x8;
typedef __attribute__((ext_vector_type(4))) float f32x4;
typedef __attribute__((ext_vector_type(8))) u16 u16x8;

__device__ __forceinline__ u16 f2b(float f) {
  union { float f; unsigned u; } v; v.f = f;
  return (u16)((v.u + 0x7fffu + ((v.u >> 16) & 1u)) >> 16);
}
__device__ __forceinline__ float b2f(u16 h) {
  union { unsigned u; float f; } v; v.u = ((unsigned)h) << 16;
  return v.f;
}
__device__ __forceinline__ f32x4 mfma16(bf16x8 a, bf16x8 b, f32x4 c) {
  return __builtin_amdgcn_mfma_f32_16x16x32_bf16(a, b, c, 0, 0, 0);
}
__device__ __forceinline__ void gl_lds16(const void* g, void* l) {
  __builtin_amdgcn_global_load_lds(
      (const __attribute__((address_space(1))) void*)g,
      (__attribute__((address_space(3))) void*)l, 16, 0, 0);
}
__device__ __forceinline__ u16x8 cvt8(float4 a, float4 b) {
  u16x8 o;
  o[0] = f2b(a.x); o[1] = f2b(a.y); o[2] = f2b(a.z); o[3] = f2b(a.w);
  o[4] = f2b(b.x); o[5] = f2b(b.y); o[6] = f2b(b.z); o[7] = f2b(b.w);
  return o;
}
__device__ __forceinline__ u16x8 cvt8v(f32x4 a, f32x4 b) {
  u16x8 o;
  o[0] = f2b(a[0]); o[1] = f2b(a[1]); o[2] = f2b(a[2]); o[3] = f2b(a[3]);
  o[4] = f2b(b[0]); o[5] = f2b(b[1]); o[6] = f2b(b[2]); o[7] = f2b(b[3]);
  return o;
}

// ---------------- weight transpose+cast: src f32 [R,C] -> dst bf16 [C][R] (linear) ----------
__global__ __launch_bounds__(256) void transpose_cast(
    const float* __restrict__ src, u16* __restrict__ dst,
    int R, int C, int dstStride, long srcBatch, long dstBatch)
{
  __shared__ float tile[32][33];
  src += (long)blockIdx.z * srcBatch;
  dst += (long)blockIdx.z * dstBatch;
  const int c0 = blockIdx.x * 32, r0 = blockIdx.y * 32;
  const int tx = threadIdx.x & 31, ty = threadIdx.x >> 5;
  for (int i = ty; i < 32; i += 8) {
    int r = r0 + i, cc = c0 + tx;
    if (r < R && cc < C) tile[i][tx] = src[(long)r * C + cc];
  }
  __syncthreads();
  for (int i = ty; i < 32; i += 8) {
    int cc = c0 + i, r = r0 + tx;
    if (cc < C && r < R) dst[(long)cc * dstStride + r] = f2b(tile[tx][i]);
  }
}

// ---- var weights -> 16KB tiles [128 nOut][64 k], chunk(n,l) = n*8 + (l^(n&7)), l=k/8.
// 32 tiles/var: Wa tiles 0..7 (kc*2+pan), Wi 8..15, Wglu 16..31 (kc*4+pan).
__global__ __launch_bounds__(256) void var_prep16(
    const float* __restrict__ W, u16* __restrict__ dstbase, int srcN, int tileBase)
{
  const int v = blockIdx.x;
  const int ti = blockIdx.y;
  const int nPanels = srcN >> 7;
  const int kc = ti / nPanels, pan = ti % nPanels;
  const int k0 = kc * 64, nOut0 = pan * 128;
  const float* src = W + (size_t)v * 256 * srcN;
  u16* dst = dstbase + (size_t)v * 262144 + (size_t)(tileBase + ti) * 8192;
  const int n = threadIdx.x & 127, lg = threadIdx.x >> 7;
#pragma unroll
  for (int ll = 0; ll < 4; ++ll) {
    const int l = lg * 4 + ll;
    u16x8 o;
#pragma unroll
    for (int e = 0; e < 8; ++e)
      o[e] = f2b(src[(size_t)(k0 + l * 8 + e) * srcN + nOut0 + n]);
    const int chunk = n * 8 + (l ^ (n & 7));
    *(u16x8*)&dst[chunk * 8] = o;
  }
}

// ---------------- gemm1 ----------------
#define K1TOT 4352
__global__ __launch_bounds__(256, 3) void gemm1(
    const float* __restrict__ x, const float* __restrict__ ctx,
    const u16* __restrict__ bt1, const float* __restrict__ ba,
    const float* __restrict__ bskip, u16* __restrict__ a_bf, float* __restrict__ skip_f)
{
  __shared__ u16 As[32 * 64];
  __shared__ u16 Bs[288 * 64];
  const int tid = threadIdx.x;
  const int n0 = blockIdx.x * 32;
  const int w = tid >> 6, lane = tid & 63;
  const int q = lane >> 4, c = lane & 15;
  const int rt = w & 1, cg = w >> 1;
  const int t0 = cg ? 9 : 0;
  const int nt = cg ? 8 : 9;

  f32x4 acc[9];
#pragma unroll
  for (int i = 0; i < 9; ++i) acc[i] = f32x4{0.f, 0.f, 0.f, 0.f};

  const int sr = tid >> 3, sp = tid & 7;
  const int sl = sp ^ (sr & 7);

  for (int kb = 0; kb < K1TOT; kb += 64) {
    {
      const float* s = (kb < 4096)
          ? (x + (size_t)(n0 + sr) * 4096 + kb + sl * 8)
          : (ctx + (size_t)(n0 + sr) * 256 + (kb - 4096) + sl * 8);
      float4 v0 = ((const float4*)s)[0];
      float4 v1 = ((const float4*)s)[1];
      *(u16x8*)&As[tid * 8] = cvt8(v0, v1);
    }
#pragma unroll
    for (int i = 0; i < 9; ++i) {
      const int cb = (i * 4 + w) * 64;
      const int cid = cb + lane;
      const int row = cid >> 3, p = cid & 7;
      const int l = p ^ (row & 7);
      const u16* src = (row < 272) ? (bt1 + (size_t)row * K1TOT + kb + l * 8) : bt1;
      gl_lds16(src, &Bs[cb * 8]);
    }
    __syncthreads();
#pragma unroll
    for (int kk = 0; kk < 2; ++kk) {
      const int arow = rt * 16 + c;
      bf16x8 af = *(const bf16x8*)&As[(arow * 64 + kk * 32 + q * 8) ^ ((arow & 7) << 3)];
#pragma unroll
      for (int ti = 0; ti < 9; ++ti) {
        if (ti < nt) {
          const int n16 = (t0 + ti) * 16 + c;
          bf16x8 bfr = *(const bf16x8*)&Bs[(n16 * 64 + kk * 32 + q * 8) ^ ((n16 & 7) << 3)];
          acc[ti] = mfma16(af, bfr, acc[ti]);
        }
      }
    }
    __syncthreads();
  }
#pragma unroll
  for (int ti = 0; ti < 9; ++ti) {
    if (ti < nt) {
      const int col = (t0 + ti) * 16 + c;
#pragma unroll
      for (int j = 0; j < 4; ++j) {
        const long n = n0 + rt * 16 + q * 4 + j;
        float vv = acc[ti][j];
        if (col < 256) {
          vv += ba[col];
          vv = vv > 0.f ? vv : expm1f(vv);
          a_bf[n * 256 + col] = f2b(vv);
        } else {
          skip_f[n * 16 + (col - 256)] = vv + bskip[col - 256];
        }
      }
    }
  }
}

// ---------------- gemm_i ----------------
__global__ __launch_bounds__(256, 3) void gemm_i(
    const u16* __restrict__ a_bf, const u16* __restrict__ wiT,
    const float* __restrict__ bi, u16* __restrict__ i_bf)
{
  __shared__ u16 As[32 * 64];
  __shared__ u16 Bs[256 * 64];
  const int tid = threadIdx.x;
  const int n0 = blockIdx.x * 32;
  const int w = tid >> 6, lane = tid & 63;
  const int q = lane >> 4, c = lane & 15;
  const int rt = w & 1, cg = w >> 1;

  f32x4 acc[8];
#pragma unroll
  for (int i = 0; i < 8; ++i) acc[i] = f32x4{0.f, 0.f, 0.f, 0.f};

  for (int kb = 0; kb < 256; kb += 64) {
    {
      const int row = tid >> 3, p = tid & 7;
      const int l = p ^ (row & 7);
      gl_lds16(a_bf + (size_t)(n0 + row) * 256 + kb + l * 8, &As[w * 512]);
    }
#pragma unroll
    for (int i = 0; i < 8; ++i) {
      const int cb = (i * 4 + w) * 64;
      const int cid = cb + lane;
      const int row = cid >> 3, p = cid & 7;
      const int l = p ^ (row & 7);
      gl_lds16(wiT + (size_t)row * 256 + kb + l * 8, &Bs[cb * 8]);
    }
    __syncthreads();
#pragma unroll
    for (int kk = 0; kk < 2; ++kk) {
      const int arow = rt * 16 + c;
      bf16x8 af = *(const bf16x8*)&As[(arow * 64 + kk * 32 + q * 8) ^ ((arow & 7) << 3)];
#pragma unroll
      for (int ti = 0; ti < 8; ++ti) {
        const int n16 = (cg * 8 + ti) * 16 + c;
        bf16x8 bfr = *(const bf16x8*)&Bs[(n16 * 64 + kk * 32 + q * 8) ^ ((n16 & 7) << 3)];
        acc[ti] = mfma16(af, bfr, acc[ti]);
      }
    }
    __syncthreads();
  }
#pragma unroll
  for (int ti = 0; ti < 8; ++ti) {
    const int col = (cg * 8 + ti) * 16 + c;
    const float bb = bi[col];
#pragma unroll
    for (int j = 0; j < 4; ++j) {
      const long n = n0 + rt * 16 + q * 4 + j;
      i_bf[n * 256 + col] = f2b(acc[ti][j] + bb);
    }
  }
}

// ---------------- joint tail ----------------
__global__ __launch_bounds__(256) void joint_tail(
    const u16* __restrict__ i_bf, const u16* __restrict__ wgluT,
    const float* __restrict__ bglu, const float* __restrict__ skip_f,
    const float* __restrict__ lng, const float* __restrict__ lnb,
    float* __restrict__ swout)
{
  __shared__ float wlds[32 * 257];
  __shared__ float ilds[4][256];
  const int tid = threadIdx.x;
  for (int jj = 0; jj < 32; ++jj) wlds[jj * 257 + tid] = b2f(wgluT[jj * 256 + tid]);
  const int w = tid >> 6, lane = tid & 63;
  const long n = (long)blockIdx.x * 4 + w;
  {
    const u16* src = i_bf + n * 256 + lane * 4;
    float4 f;
    f.x = b2f(src[0]); f.y = b2f(src[1]); f.z = b2f(src[2]); f.w = b2f(src[3]);
    *(float4*)&ilds[w][lane * 4] = f;
  }
  __syncthreads();
  const int cc32 = lane & 31;
  const int k0 = (lane >> 5) * 128;
  float acc = 0.f;
  for (int k = 0; k < 128; ++k) acc += ilds[w][k0 + k] * wlds[cc32 * 257 + k0 + k];
  acc += __shfl_xor(acc, 32, 64);
  const float gfull = acc + bglu[cc32];
  const int cc = lane & 15;
  const float g1 = __shfl(gfull, cc, 64);
  const float g2 = __shfl(gfull, cc + 16, 64);
  const float glu = g1 / (1.f + __expf(-g2));
  const float y = glu + skip_f[n * 16 + cc];
  float s = y, ss = y * y;
#pragma unroll
  for (int d = 1; d < 16; d <<= 1) { s += __shfl_xor(s, d, 64); ss += __shfl_xor(ss, d, 64); }
  const float m = s * (1.f / 16.f);
  const float var = ss * (1.f / 16.f) - m * m;
  const float t = (y - m) * rsqrtf(var + 1e-5f) * lng[cc] + lnb[cc];
  float mx = t;
#pragma unroll
  for (int d = 1; d < 16; d <<= 1) mx = fmaxf(mx, __shfl_xor(mx, d, 64));
  const float e = __expf(t - mx);
  float es = e;
#pragma unroll
  for (int d = 1; d < 16; d <<= 1) es += __shfl_xor(es, d, 64);
  if (lane < 16) swout[n * 16 + lane] = e / es;
}

// ---------------- reduce over 4 var-group partials ----------------
__global__ __launch_bounds__(256) void reduce4(
    const float* __restrict__ part, float* __restrict__ out)
{
  const size_t i = ((size_t)blockIdx.x * 256 + threadIdx.x) * 4;
  float4 a = *(const float4*)(part + i);
  float4 b = *(const float4*)(part + i + 2097152);
  float4 c = *(const float4*)(part + i + 4194304);
  float4 d = *(const float4*)(part + i + 6291456);
  float4 o;
  o.x = a.x + b.x + c.x + d.x;
  o.y = a.y + b.y + c.y + d.y;
  o.z = a.z + b.z + c.z + d.z;
  o.w = a.w + b.w + c.w + d.w;
  *(float4*)(out + i) = o;
}

// ---------------- per-variable fused chain v10: 64KB slots, ring-2, 32 rounds ----------
// R20/R21 body; slot = 4 consecutive 16KB tiles (64KB). Rounds/block 64 -> 32
// (per-round fixed overhead was the measured limiter; R21's vmcnt probe confirmed
// stage latency is hidden). Ring of 2 x 64KB; ROUND_TAIL: B1 -> STAGE64(buf[s%2],
// s+2) -> vmcnt(8) [16 in flight; oldest 8 = slot s+1 resident] -> B2.
// m1/m2 round r: kc in {2r,2r+1} x both panels (tile tt = 2*kk2+h);
// m3 round r: kc=r x all 4 quarters (tt = h). Accumulators unchanged.
// LDS: xt 16KB + 2x64KB + red 2.25KB = 149.8KB (1 block/CU).
__global__ __launch_bounds__(512, 2) void var_chain(
    const float* __restrict__ x, const u16* __restrict__ varw,
    const float* __restrict__ vba, const float* __restrict__ vbi,
    const float* __restrict__ vbglu, const float* __restrict__ vlng,
    const float* __restrict__ vlnb, const float* __restrict__ sw,
    float* __restrict__ outp)
{
  extern __shared__ u16 smem[];
  u16* const xt  = smem;                        // 8192 u16 (16KB): x -> av -> iv
  u16* const wtb = smem + 8192;                 // 2 x 32768 u16 (2 x 64KB slot ring)
  float* const red   = (float*)(smem + 73728);  // [32][16] f32 (2KB)
  float* const muinv = red + 512;               // [32][2] f32

  const int tid = threadIdx.x;
  const int w = tid >> 6, lane = tid & 63;
  const int q = lane >> 4, c = lane & 15;
  const int vbase = blockIdx.x * 4;
  const int n0 = blockIdx.y * 32;
  const int nloc = w * 16 + c;                  // B-read row within 128-panel
  const int bsw7 = nloc & 7;

  f32x4 outacc[2][2];
#pragma unroll
  for (int p = 0; p < 2; ++p)
#pragma unroll
    for (int u = 0; u < 2; ++u) outacc[p][u] = f32x4{0.f, 0.f, 0.f, 0.f};

  auto STAGE64 = [&](int b, int sn) {  // slot sn = tiles 4sn..4sn+3 -> wtb[b]; 8 loads
#pragma unroll
    for (int tt = 0; tt < 4; ++tt) {
      const int tn = 4 * sn + tt;
      const u16* tb = varw + (size_t)(vbase + (tn >> 5)) * 262144 + (size_t)(tn & 31) * 8192;
      u16* dst = wtb + b * 32768 + tt * 8192;
#pragma unroll
      for (int i = 0; i < 2; ++i) {
        const int cb = (i * 8 + w) * 64;
        gl_lds16(tb + (size_t)(cb + lane) * 8, dst + (size_t)cb * 8);
      }
    }
  };
  auto XSTAGE = [&](int v) {  // xt = 32x256 x-tile (nontemporal, swizzle pre-baked)
#pragma unroll
    for (int jj = 0; jj < 2; ++jj) {
      const int cid = jj * 512 + tid;
      const int r = cid >> 5, p5 = cid & 31;
      const int l = (p5 & 24) | ((p5 & 7) ^ (r & 7));
      const f32x4* s = (const f32x4*)(x + (size_t)(n0 + r) * 4096 + (size_t)v * 256 + l * 8);
      f32x4 v0 = __builtin_nontemporal_load(s);
      f32x4 v1 = __builtin_nontemporal_load(s + 1);
      *(u16x8*)&xt[cid * 8] = cvt8v(v0, v1);
    }
  };
  auto ROUND_TAIL = [&](int s) {
    __builtin_amdgcn_s_barrier();                    // B1: reads of slot s done
    __builtin_amdgcn_sched_barrier(0);
    STAGE64(s & 1, (s + 2 < 32) ? s + 2 : 31);
    __builtin_amdgcn_sched_barrier(0);
    asm volatile("s_waitcnt vmcnt(8)" ::: "memory"); // oldest 8 (slot s+1) resident
    __builtin_amdgcn_sched_barrier(0);
    __builtin_amdgcn_s_barrier();                    // B2
    __builtin_amdgcn_sched_barrier(0);
  };
  // B fragment: tile base (within slot), panel-row nloc, k-chunk l = kk*4+q
  auto BREAD = [&](const u16* wcur, int kk) -> bf16x8 {
    const int l = kk * 4 + q;
    return *(const bf16x8*)&wcur[(nloc * 8 + (l ^ bsw7)) * 8];
  };
  auto AREAD = [&](int p, int k0, int kk) -> bf16x8 {
    const int row = p * 16 + c;
    return *(const bf16x8*)&xt[(row * 256 + k0 + kk * 32 + q * 8) ^ ((row & 7) << 3)];
  };

  // prologue: slots 0,1 in flight; x for var 0; full drain
  STAGE64(0, 0); STAGE64(1, 1);
  XSTAGE(vbase);
  __syncthreads();

  int s = 0;  // global slot counter 0..31 (8 per var)
  for (int vi = 0; vi < 4; ++vi) {
    const int v = vbase + vi;

    // ---- m1: av = elu(x @ WaT + ba): 2 rounds (kc pair per round) ----
    f32x4 acc2[2][2];
#pragma unroll
    for (int p = 0; p < 2; ++p)
#pragma unroll
      for (int u = 0; u < 2; ++u) acc2[p][u] = f32x4{0.f, 0.f, 0.f, 0.f};
    for (int r = 0; r < 2; ++r, ++s) {
      const u16* wcur = wtb + (s & 1) * 32768;
      __builtin_amdgcn_s_setprio(1);
#pragma unroll
      for (int kk2 = 0; kk2 < 2; ++kk2) {      // sub-kc within slot
        const int k0 = (2 * r + kk2) * 64;
#pragma unroll
        for (int kk = 0; kk < 2; ++kk) {
          bf16x8 a0 = AREAD(0, k0, kk);
          bf16x8 a1 = AREAD(1, k0, kk);
#pragma unroll
          for (int h = 0; h < 2; ++h) {
            bf16x8 b = BREAD(wcur + (kk2 * 2 + h) * 8192, kk);
            acc2[0][h] = mfma16(a0, b, acc2[0][h]);
            acc2[1][h] = mfma16(a1, b, acc2[1][h]);
          }
        }
      }
      __builtin_amdgcn_s_setprio(0);
      ROUND_TAIL(s);
    }
    // write av into xt
#pragma unroll
    for (int p = 0; p < 2; ++p)
#pragma unroll
      for (int h = 0; h < 2; ++h) {
        const int col = h * 128 + nloc;
        const float bb = vba[v * 256 + col];
#pragma unroll
        for (int j = 0; j < 4; ++j) {
          const int row = p * 16 + q * 4 + j;
          float vv = acc2[p][h][j] + bb;
          vv = vv > 0.f ? vv : expm1f(vv);
          xt[(row * 256 + col) ^ ((row & 7) << 3)] = f2b(vv);
        }
      }
    __syncthreads();

    // ---- m2: iv = av @ WiT + bi: 2 rounds ----
#pragma unroll
    for (int p = 0; p < 2; ++p)
#pragma unroll
      for (int u = 0; u < 2; ++u) acc2[p][u] = f32x4{0.f, 0.f, 0.f, 0.f};
    for (int r = 0; r < 2; ++r, ++s) {
      const u16* wcur = wtb + (s & 1) * 32768;
      __builtin_amdgcn_s_setprio(1);
#pragma unroll
      for (int kk2 = 0; kk2 < 2; ++kk2) {
        const int k0 = (2 * r + kk2) * 64;
#pragma unroll
        for (int kk = 0; kk < 2; ++kk) {
          bf16x8 a0 = AREAD(0, k0, kk);
          bf16x8 a1 = AREAD(1, k0, kk);
#pragma unroll
          for (int h = 0; h < 2; ++h) {
            bf16x8 b = BREAD(wcur + (kk2 * 2 + h) * 8192, kk);
            acc2[0][h] = mfma16(a0, b, acc2[0][h]);
            acc2[1][h] = mfma16(a1, b, acc2[1][h]);
          }
        }
      }
      __builtin_amdgcn_s_setprio(0);
      ROUND_TAIL(s);
    }
    // write iv into xt
#pragma unroll
    for (int p = 0; p < 2; ++p)
#pragma unroll
      for (int h = 0; h < 2; ++h) {
        const int col = h * 128 + nloc;
        const float bb = vbi[v * 256 + col];
#pragma unroll
        for (int j = 0; j < 4; ++j) {
          const int row = p * 16 + q * 4 + j;
          xt[(row * 256 + col) ^ ((row & 7) << 3)] = f2b(acc2[p][h][j] + bb);
        }
      }
    __syncthreads();

    // ---- m3: gv = iv @ WgluT: 4 rounds (kc = r; all 4 quarters per round) ----
    f32x4 acc3[2][4];
#pragma unroll
    for (int p = 0; p < 2; ++p)
#pragma unroll
      for (int u = 0; u < 4; ++u) acc3[p][u] = f32x4{0.f, 0.f, 0.f, 0.f};
    for (int r = 0; r < 4; ++r, ++s) {
      const u16* wcur = wtb + (s & 1) * 32768;
      const int k0 = r * 64;
      __builtin_amdgcn_s_setprio(1);
#pragma unroll
      for (int kk = 0; kk < 2; ++kk) {
        bf16x8 a0 = AREAD(0, k0, kk);
        bf16x8 a1 = AREAD(1, k0, kk);
#pragma unroll
        for (int h = 0; h < 4; ++h) {
          bf16x8 b = BREAD(wcur + h * 8192, kk);
          acc3[0][h] = mfma16(a0, b, acc3[0][h]);
          acc3[1][h] = mfma16(a1, b, acc3[1][h]);
        }
      }
      __builtin_amdgcn_s_setprio(0);
      ROUND_TAIL(s);
    }

    // ---- epilogue: GLU + residual (NT) + LN + weighted accumulate ----
    // m3 quarters: h = pan4 = {g1p0,g1p1,g2p0,g2p1} -> g1 = acc3[.][u], g2 = acc3[.][u+2]
    float rs[2][4], rss[2][4];
#pragma unroll
    for (int p = 0; p < 2; ++p)
#pragma unroll
      for (int j = 0; j < 4; ++j) { rs[p][j] = 0.f; rss[p][j] = 0.f; }
#pragma unroll
    for (int p = 0; p < 2; ++p)
#pragma unroll
      for (int u = 0; u < 2; ++u) {
        const int col = u * 128 + nloc;
        const float b1 = vbglu[v * 512 + col];
        const float b2 = vbglu[v * 512 + 256 + col];
#pragma unroll
        for (int j = 0; j < 4; ++j) {
          const int row = p * 16 + q * 4 + j;
          const float g1 = acc3[p][u][j] + b1;
          const float g2 = acc3[p][u + 2][j] + b2;
          const float glu = g1 / (1.f + __expf(-g2));
          const float resid = __builtin_nontemporal_load(
              &x[(size_t)(n0 + row) * 4096 + (size_t)v * 256 + col]);
          const float rr = glu + resid;
          acc3[p][u][j] = rr;
          rs[p][j] += rr; rss[p][j] += rr * rr;
        }
      }
#pragma unroll
    for (int p = 0; p < 2; ++p)
#pragma unroll
      for (int j = 0; j < 4; ++j)
#pragma unroll
        for (int d = 1; d < 16; d <<= 1) {
          rs[p][j]  += __shfl_xor(rs[p][j], d, 64);
          rss[p][j] += __shfl_xor(rss[p][j], d, 64);
        }
    if (c == 0) {
#pragma unroll
      for (int p = 0; p < 2; ++p)
#pragma unroll
        for (int j = 0; j < 4; ++j) {
          const int row = p * 16 + q * 4 + j;
          red[row * 16 + w * 2]     = rs[p][j];
          red[row * 16 + w * 2 + 1] = rss[p][j];
        }
    }
    __syncthreads();
    if (tid < 32) {
      float ms = 0.f, vs = 0.f;
#pragma unroll
      for (int ww = 0; ww < 8; ++ww) { ms += red[tid * 16 + ww * 2]; vs += red[tid * 16 + ww * 2 + 1]; }
      const float mm = ms * (1.f / 256.f);
      muinv[tid * 2]     = mm;
      muinv[tid * 2 + 1] = rsqrtf(vs * (1.f / 256.f) - mm * mm + 1e-5f);
    }
    __syncthreads();
#pragma unroll
    for (int p = 0; p < 2; ++p) {
#pragma unroll
      for (int j = 0; j < 4; ++j) {
        const int row = p * 16 + q * 4 + j;
        const float mu = muinv[row * 2], inv = muinv[row * 2 + 1];
        const float wv = sw[(size_t)(n0 + row) * 16 + v];
#pragma unroll
        for (int u = 0; u < 2; ++u) {
          const int col = u * 128 + nloc;
          const float tv = (acc3[p][u][j] - mu) * inv * vlng[v * 256 + col] + vlnb[v * 256 + col];
          outacc[p][u][j] += tv * wv;
        }
      }
    }
    __syncthreads();  // muinv/red reads done before next var reuses LDS
    if (vi < 3) {
      XSTAGE(v + 1);
      __syncthreads();  // xt(x) visible; ring slots stay resident
    }
  }

  // plain stores to this var-group's private partial buffer
  float* const dst = outp + (size_t)blockIdx.x * 2097152;
#pragma unroll
  for (int p = 0; p < 2; ++p)
#pragma unroll
    for (int u = 0; u < 2; ++u) {
      const int col = u * 128 + nloc;
#pragma unroll
      for (int j = 0; j < 4; ++j) {
        const int row = p * 16 + q * 4 + j;
        dst[(size_t)(n0 + row) * 256 + col] = outacc[p][u][j];
      }
    }
}

extern "C" void kernel_launch(void* const* d_in, const int* in_sizes, int n_in,
                              void* d_out, int out_size, void* d_ws, size_t ws_size,
                              hipStream_t stream) {
  const float* x     = (const float*)d_in[0];
  const float* ctx   = (const float*)d_in[1];
  const float* jWa   = (const float*)d_in[2];
  const float* jba   = (const float*)d_in[3];
  const float* jWc   = (const float*)d_in[4];
  const float* jWi   = (const float*)d_in[5];
  const float* jbi   = (const float*)d_in[6];
  const float* jWglu = (const float*)d_in[7];
  const float* jbglu = (const float*)d_in[8];
  const float* jWskip= (const float*)d_in[9];
  const float* jbskip= (const float*)d_in[10];
  const float* jlng  = (const float*)d_in[11];
  const float* jlnb  = (const float*)d_in[12];
  const float* vWa   = (const float*)d_in[13];
  const float* vba   = (const float*)d_in[14];
  const float* vWi   = (const float*)d_in[15];
  const float* vbi   = (const float*)d_in[16];
  const float* vWglu = (const float*)d_in[17];
  const float* vbglu = (const float*)d_in[18];
  const float* vlng  = (const float*)d_in[19];
  const float* vlnb  = (const float*)d_in[20];
  float* out = (float*)d_out;

  char* ws = (char*)d_ws;
  size_t off = 0;
  auto alloc = [&](size_t bytes) { void* p = ws + off; off += (bytes + 255) & ~(size_t)255; return p; };
  u16* bt1     = (u16*)alloc((size_t)272 * 4352 * 2);
  u16* wiT     = (u16*)alloc((size_t)256 * 256 * 2);
  u16* wgluT   = (u16*)alloc((size_t)32 * 256 * 2);
  u16* varw    = (u16*)alloc((size_t)16 * 262144 * 2);   // 16 vars x 32 tiles x 16KB
  u16* a_bf    = (u16*)alloc((size_t)8192 * 256 * 2);
  u16* i_bf    = (u16*)alloc((size_t)8192 * 256 * 2);
  float* skipf = (float*)alloc((size_t)8192 * 16 * 4);
  float* outp  = (float*)alloc((size_t)4 * 8192 * 256 * 4); // 32 MB partials

  hipMemsetAsync(bt1, 0, (size_t)272 * 4352 * 2, stream);

  dim3 blk(256);
  transpose_cast<<<dim3(8, 128, 1),  blk, 0, stream>>>(jWa,   bt1,              4096, 256, 4352, 0, 0);
  transpose_cast<<<dim3(8, 8, 1),    blk, 0, stream>>>(jWc,   bt1 + 4096,       256,  256, 4352, 0, 0);
  transpose_cast<<<dim3(1, 128, 1),  blk, 0, stream>>>(jWskip,bt1 + 256 * 4352, 4096, 16,  4352, 0, 0);
  transpose_cast<<<dim3(8, 8, 1),    blk, 0, stream>>>(jWi,   wiT,   256, 256, 256, 0, 0);
  transpose_cast<<<dim3(1, 8, 1),    blk, 0, stream>>>(jWglu, wgluT, 256, 32,  256, 0, 0);
  var_prep16<<<dim3(16, 8),  blk, 0, stream>>>(vWa,   varw, 256, 0);
  var_prep16<<<dim3(16, 8),  blk, 0, stream>>>(vWi,   varw, 256, 8);
  var_prep16<<<dim3(16, 16), blk, 0, stream>>>(vWglu, varw, 512, 16);

  gemm1<<<dim3(256), blk, 0, stream>>>(x, ctx, bt1, jba, jbskip, a_bf, skipf);
  gemm_i<<<dim3(256), blk, 0, stream>>>(a_bf, wiT, jbi, i_bf);
  joint_tail<<<dim3(2048), blk, 0, stream>>>(i_bf, wgluT, jbglu, skipf, jlng, jlnb,
                                             out + (size_t)8192 * 256);

  hipFuncSetAttribute((const void*)var_chain, hipFuncAttributeMaxDynamicSharedMemorySize, 153600);
  var_chain<<<dim3(4, 256), dim3(512), 153600, stream>>>(x, varw, vba, vbi, vbglu,
                                                         vlng, vlnb,
                                                         out + (size_t)8192 * 256, outp);
  reduce4<<<dim3(2048), blk, 0, stream>>>(outp, out);
}

// Round 23
// 420.833 us; speedup vs baseline: 1.0090x; 1.0090x over previous
//
#include <hip/hip_runtime.h>

typedef unsigned short u16;
typedef __attribute__((ext_vector_type(8))) __bf16 bf16x8;
typedef __attribute__((ext_vector_type(4))) float f32x4;
typedef __attribute__((ext_vector_type(8))) u16 u16x8;

__device__ __forceinline__ u16 f2b(float f) {
  union { float f; unsigned u; } v; v.f = f;
  return (u16)((v.u + 0x7fffu + ((v.u >> 16) & 1u)) >> 16);
}
__device__ __forceinline__ float b2f(u16 h) {
  union { unsigned u; float f; } v; v.u = ((unsigned)h) << 16;
  return v.f;
}
__device__ __forceinline__ f32x4 mfma16(bf16x8 a, bf16x8 b, f32x4 c) {
  return __builtin_amdgcn_mfma_f32_16x16x32_bf16(a, b, c, 0, 0, 0);
}
__device__ __forceinline__ void gl_lds16(const void* g, void* l) {
  __builtin_amdgcn_global_load_lds(
      (const __attribute__((address_space(1))) void*)g,
      (__attribute__((address_space(3))) void*)l, 16, 0, 0);
}
__device__ __forceinline__ u16x8 cvt8(float4 a, float4 b) {
  u16x8 o;
  o[0] = f2b(a.x); o[1] = f2b(a.y); o[2] = f2b(a.z); o[3] = f2b(a.w);
  o[4] = f2b(b.x); o[5] = f2b(b.y); o[6] = f2b(b.z); o[7] = f2b(b.w);
  return o;
}
__device__ __forceinline__ u16x8 cvt8v(f32x4 a, f32x4 b) {
  u16x8 o;
  o[0] = f2b(a[0]); o[1] = f2b(a[1]); o[2] = f2b(a[2]); o[3] = f2b(a[3]);
  o[4] = f2b(b[0]); o[5] = f2b(b[1]); o[6] = f2b(b[2]); o[7] = f2b(b[3]);
  return o;
}

// ---------------- weight transpose+cast: src f32 [R,C] -> dst bf16 [C][R] (linear) ----------
__global__ __launch_bounds__(256) void transpose_cast(
    const float* __restrict__ src, u16* __restrict__ dst,
    int R, int C, int dstStride, long srcBatch, long dstBatch)
{
  __shared__ float tile[32][33];
  src += (long)blockIdx.z * srcBatch;
  dst += (long)blockIdx.z * dstBatch;
  const int c0 = blockIdx.x * 32, r0 = blockIdx.y * 32;
  const int tx = threadIdx.x & 31, ty = threadIdx.x >> 5;
  for (int i = ty; i < 32; i += 8) {
    int r = r0 + i, cc = c0 + tx;
    if (r < R && cc < C) tile[i][tx] = src[(long)r * C + cc];
  }
  __syncthreads();
  for (int i = ty; i < 32; i += 8) {
    int cc = c0 + i, r = r0 + tx;
    if (cc < C && r < R) dst[(long)cc * dstStride + r] = f2b(tile[tx][i]);
  }
}

// ---- var weights -> 16KB tiles [128 nOut][64 k], chunk(n,l) = n*8 + (l^(n&7)), l=k/8.
// 32 tiles/var: Wa tiles 0..7 (kc*2+pan), Wi 8..15, Wglu 16..31 (kc*4+pan).
__global__ __launch_bounds__(256) void var_prep16(
    const float* __restrict__ W, u16* __restrict__ dstbase, int srcN, int tileBase)
{
  const int v = blockIdx.x;
  const int ti = blockIdx.y;
  const int nPanels = srcN >> 7;
  const int kc = ti / nPanels, pan = ti % nPanels;
  const int k0 = kc * 64, nOut0 = pan * 128;
  const float* src = W + (size_t)v * 256 * srcN;
  u16* dst = dstbase + (size_t)v * 262144 + (size_t)(tileBase + ti) * 8192;
  const int n = threadIdx.x & 127, lg = threadIdx.x >> 7;
#pragma unroll
  for (int ll = 0; ll < 4; ++ll) {
    const int l = lg * 4 + ll;
    u16x8 o;
#pragma unroll
    for (int e = 0; e < 8; ++e)
      o[e] = f2b(src[(size_t)(k0 + l * 8 + e) * srcN + nOut0 + n]);
    const int chunk = n * 8 + (l ^ (n & 7));
    *(u16x8*)&dst[chunk * 8] = o;
  }
}

// ---------------- gemm1 ----------------
#define K1TOT 4352
__global__ __launch_bounds__(256, 3) void gemm1(
    const float* __restrict__ x, const float* __restrict__ ctx,
    const u16* __restrict__ bt1, const float* __restrict__ ba,
    const float* __restrict__ bskip, u16* __restrict__ a_bf, float* __restrict__ skip_f)
{
  __shared__ u16 As[32 * 64];
  __shared__ u16 Bs[288 * 64];
  const int tid = threadIdx.x;
  const int n0 = blockIdx.x * 32;
  const int w = tid >> 6, lane = tid & 63;
  const int q = lane >> 4, c = lane & 15;
  const int rt = w & 1, cg = w >> 1;
  const int t0 = cg ? 9 : 0;
  const int nt = cg ? 8 : 9;

  f32x4 acc[9];
#pragma unroll
  for (int i = 0; i < 9; ++i) acc[i] = f32x4{0.f, 0.f, 0.f, 0.f};

  const int sr = tid >> 3, sp = tid & 7;
  const int sl = sp ^ (sr & 7);

  for (int kb = 0; kb < K1TOT; kb += 64) {
    {
      const float* s = (kb < 4096)
          ? (x + (size_t)(n0 + sr) * 4096 + kb + sl * 8)
          : (ctx + (size_t)(n0 + sr) * 256 + (kb - 4096) + sl * 8);
      float4 v0 = ((const float4*)s)[0];
      float4 v1 = ((const float4*)s)[1];
      *(u16x8*)&As[tid * 8] = cvt8(v0, v1);
    }
#pragma unroll
    for (int i = 0; i < 9; ++i) {
      const int cb = (i * 4 + w) * 64;
      const int cid = cb + lane;
      const int row = cid >> 3, p = cid & 7;
      const int l = p ^ (row & 7);
      const u16* src = (row < 272) ? (bt1 + (size_t)row * K1TOT + kb + l * 8) : bt1;
      gl_lds16(src, &Bs[cb * 8]);
    }
    __syncthreads();
#pragma unroll
    for (int kk = 0; kk < 2; ++kk) {
      const int arow = rt * 16 + c;
      bf16x8 af = *(const bf16x8*)&As[(arow * 64 + kk * 32 + q * 8) ^ ((arow & 7) << 3)];
#pragma unroll
      for (int ti = 0; ti < 9; ++ti) {
        if (ti < nt) {
          const int n16 = (t0 + ti) * 16 + c;
          bf16x8 bfr = *(const bf16x8*)&Bs[(n16 * 64 + kk * 32 + q * 8) ^ ((n16 & 7) << 3)];
          acc[ti] = mfma16(af, bfr, acc[ti]);
        }
      }
    }
    __syncthreads();
  }
#pragma unroll
  for (int ti = 0; ti < 9; ++ti) {
    if (ti < nt) {
      const int col = (t0 + ti) * 16 + c;
#pragma unroll
      for (int j = 0; j < 4; ++j) {
        const long n = n0 + rt * 16 + q * 4 + j;
        float vv = acc[ti][j];
        if (col < 256) {
          vv += ba[col];
          vv = vv > 0.f ? vv : expm1f(vv);
          a_bf[n * 256 + col] = f2b(vv);
        } else {
          skip_f[n * 16 + (col - 256)] = vv + bskip[col - 256];
        }
      }
    }
  }
}

// ---------------- gemm_i ----------------
__global__ __launch_bounds__(256, 3) void gemm_i(
    const u16* __restrict__ a_bf, const u16* __restrict__ wiT,
    const float* __restrict__ bi, u16* __restrict__ i_bf)
{
  __shared__ u16 As[32 * 64];
  __shared__ u16 Bs[256 * 64];
  const int tid = threadIdx.x;
  const int n0 = blockIdx.x * 32;
  const int w = tid >> 6, lane = tid & 63;
  const int q = lane >> 4, c = lane & 15;
  const int rt = w & 1, cg = w >> 1;

  f32x4 acc[8];
#pragma unroll
  for (int i = 0; i < 8; ++i) acc[i] = f32x4{0.f, 0.f, 0.f, 0.f};

  for (int kb = 0; kb < 256; kb += 64) {
    {
      const int row = tid >> 3, p = tid & 7;
      const int l = p ^ (row & 7);
      gl_lds16(a_bf + (size_t)(n0 + row) * 256 + kb + l * 8, &As[w * 512]);
    }
#pragma unroll
    for (int i = 0; i < 8; ++i) {
      const int cb = (i * 4 + w) * 64;
      const int cid = cb + lane;
      const int row = cid >> 3, p = cid & 7;
      const int l = p ^ (row & 7);
      gl_lds16(wiT + (size_t)row * 256 + kb + l * 8, &Bs[cb * 8]);
    }
    __syncthreads();
#pragma unroll
    for (int kk = 0; kk < 2; ++kk) {
      const int arow = rt * 16 + c;
      bf16x8 af = *(const bf16x8*)&As[(arow * 64 + kk * 32 + q * 8) ^ ((arow & 7) << 3)];
#pragma unroll
      for (int ti = 0; ti < 8; ++ti) {
        const int n16 = (cg * 8 + ti) * 16 + c;
        bf16x8 bfr = *(const bf16x8*)&Bs[(n16 * 64 + kk * 32 + q * 8) ^ ((n16 & 7) << 3)];
        acc[ti] = mfma16(af, bfr, acc[ti]);
      }
    }
    __syncthreads();
  }
#pragma unroll
  for (int ti = 0; ti < 8; ++ti) {
    const int col = (cg * 8 + ti) * 16 + c;
    const float bb = bi[col];
#pragma unroll
    for (int j = 0; j < 4; ++j) {
      const long n = n0 + rt * 16 + q * 4 + j;
      i_bf[n * 256 + col] = f2b(acc[ti][j] + bb);
    }
  }
}

// ---------------- joint tail ----------------
__global__ __launch_bounds__(256) void joint_tail(
    const u16* __restrict__ i_bf, const u16* __restrict__ wgluT,
    const float* __restrict__ bglu, const float* __restrict__ skip_f,
    const float* __restrict__ lng, const float* __restrict__ lnb,
    float* __restrict__ swout)
{
  __shared__ float wlds[32 * 257];
  __shared__ float ilds[4][256];
  const int tid = threadIdx.x;
  for (int jj = 0; jj < 32; ++jj) wlds[jj * 257 + tid] = b2f(wgluT[jj * 256 + tid]);
  const int w = tid >> 6, lane = tid & 63;
  const long n = (long)blockIdx.x * 4 + w;
  {
    const u16* src = i_bf + n * 256 + lane * 4;
    float4 f;
    f.x = b2f(src[0]); f.y = b2f(src[1]); f.z = b2f(src[2]); f.w = b2f(src[3]);
    *(float4*)&ilds[w][lane * 4] = f;
  }
  __syncthreads();
  const int cc32 = lane & 31;
  const int k0 = (lane >> 5) * 128;
  float acc = 0.f;
  for (int k = 0; k < 128; ++k) acc += ilds[w][k0 + k] * wlds[cc32 * 257 + k0 + k];
  acc += __shfl_xor(acc, 32, 64);
  const float gfull = acc + bglu[cc32];
  const int cc = lane & 15;
  const float g1 = __shfl(gfull, cc, 64);
  const float g2 = __shfl(gfull, cc + 16, 64);
  const float glu = g1 / (1.f + __expf(-g2));
  const float y = glu + skip_f[n * 16 + cc];
  float s = y, ss = y * y;
#pragma unroll
  for (int d = 1; d < 16; d <<= 1) { s += __shfl_xor(s, d, 64); ss += __shfl_xor(ss, d, 64); }
  const float m = s * (1.f / 16.f);
  const float var = ss * (1.f / 16.f) - m * m;
  const float t = (y - m) * rsqrtf(var + 1e-5f) * lng[cc] + lnb[cc];
  float mx = t;
#pragma unroll
  for (int d = 1; d < 16; d <<= 1) mx = fmaxf(mx, __shfl_xor(mx, d, 64));
  const float e = __expf(t - mx);
  float es = e;
#pragma unroll
  for (int d = 1; d < 16; d <<= 1) es += __shfl_xor(es, d, 64);
  if (lane < 16) swout[n * 16 + lane] = e / es;
}

// ---------------- reduce over 4 var-group partials ----------------
__global__ __launch_bounds__(256) void reduce4(
    const float* __restrict__ part, float* __restrict__ out)
{
  const size_t i = ((size_t)blockIdx.x * 256 + threadIdx.x) * 4;
  float4 a = *(const float4*)(part + i);
  float4 b = *(const float4*)(part + i + 2097152);
  float4 c = *(const float4*)(part + i + 4194304);
  float4 d = *(const float4*)(part + i + 6291456);
  float4 o;
  o.x = a.x + b.x + c.x + d.x;
  o.y = a.y + b.y + c.y + d.y;
  o.z = a.z + b.z + c.z + d.z;
  o.w = a.w + b.w + c.w + d.w;
  *(float4*)(out + i) = o;
}

// ---------------- per-variable fused chain (FINAL = R20 best): 32KB slot rounds --------
// Session-best measured config (421.8 us total, var_chain 257 us): ring of 3 x 32KB
// slots, 64 rounds/block, counted vmcnt(4), (512,2) spill-free (VGPR=108),
// grid (4,256) -> one var-group (2MB weights) per XCD, f32 partials + reduce4.
__global__ __launch_bounds__(512, 2) void var_chain(
    const float* __restrict__ x, const u16* __restrict__ varw,
    const float* __restrict__ vba, const float* __restrict__ vbi,
    const float* __restrict__ vbglu, const float* __restrict__ vlng,
    const float* __restrict__ vlnb, const float* __restrict__ sw,
    float* __restrict__ outp)
{
  extern __shared__ u16 smem[];
  u16* const xt  = smem;                        // 8192 u16 (16KB): x -> av -> iv
  u16* const wtb = smem + 8192;                 // 3 x 16384 u16 (3 x 32KB slot ring)
  float* const red   = (float*)(smem + 57344);  // [32][16] f32 (2KB)
  float* const muinv = red + 512;               // [32][2] f32

  const int tid = threadIdx.x;
  const int w = tid >> 6, lane = tid & 63;
  const int q = lane >> 4, c = lane & 15;
  const int vbase = blockIdx.x * 4;
  const int n0 = blockIdx.y * 32;
  const int nloc = w * 16 + c;                  // B-read row within 128-panel
  const int bsw7 = nloc & 7;

  f32x4 outacc[2][2];
#pragma unroll
  for (int p = 0; p < 2; ++p)
#pragma unroll
    for (int u = 0; u < 2; ++u) outacc[p][u] = f32x4{0.f, 0.f, 0.f, 0.f};

  auto STAGE32 = [&](int b, int s) {  // slot s = tiles 2s,2s+1 -> wtb[b]; 4 loads/thread
#pragma unroll
    for (int tt = 0; tt < 2; ++tt) {
      const int tn = 2 * s + tt;
      const u16* tb = varw + (size_t)(vbase + (tn >> 5)) * 262144 + (size_t)(tn & 31) * 8192;
      u16* dst = wtb + b * 16384 + tt * 8192;
#pragma unroll
      for (int i = 0; i < 2; ++i) {
        const int cb = (i * 8 + w) * 64;
        gl_lds16(tb + (size_t)(cb + lane) * 8, dst + (size_t)cb * 8);
      }
    }
  };
  auto XSTAGE = [&](int v) {  // xt = 32x256 x-tile (nontemporal, swizzle pre-baked)
#pragma unroll
    for (int jj = 0; jj < 2; ++jj) {
      const int cid = jj * 512 + tid;
      const int r = cid >> 5, p5 = cid & 31;
      const int l = (p5 & 24) | ((p5 & 7) ^ (r & 7));
      const f32x4* s = (const f32x4*)(x + (size_t)(n0 + r) * 4096 + (size_t)v * 256 + l * 8);
      f32x4 v0 = __builtin_nontemporal_load(s);
      f32x4 v1 = __builtin_nontemporal_load(s + 1);
      *(u16x8*)&xt[cid * 8] = cvt8v(v0, v1);
    }
  };
  auto ROUND_TAIL = [&](int s) {
    __builtin_amdgcn_s_barrier();                    // B1: reads of slot s done
    __builtin_amdgcn_sched_barrier(0);
    STAGE32(s % 3, (s + 3 < 64) ? s + 3 : 63);
    __builtin_amdgcn_sched_barrier(0);
    asm volatile("s_waitcnt vmcnt(4)" ::: "memory"); // slot s+1/s+2 resident
    __builtin_amdgcn_sched_barrier(0);
    __builtin_amdgcn_s_barrier();                    // B2
    __builtin_amdgcn_sched_barrier(0);
  };
  // B fragment: tile base (within slot), panel-row nloc, k-chunk l = kk*4+q
  auto BREAD = [&](const u16* wcur, int kk) -> bf16x8 {
    const int l = kk * 4 + q;
    return *(const bf16x8*)&wcur[(nloc * 8 + (l ^ bsw7)) * 8];
  };
  auto AREAD = [&](int p, int k0, int kk) -> bf16x8 {
    const int row = p * 16 + c;
    return *(const bf16x8*)&xt[(row * 256 + k0 + kk * 32 + q * 8) ^ ((row & 7) << 3)];
  };

  // prologue: slots 0,1,2 in flight; x for var 0; full drain
  STAGE32(0, 0); STAGE32(1, 1); STAGE32(2, 2);
  XSTAGE(vbase);
  __syncthreads();

  int s = 0;  // global slot counter 0..63 (16 per var)
  for (int vi = 0; vi < 4; ++vi) {
    const int v = vbase + vi;

    // ---- m1: av = elu(x @ WaT + ba): 4 rounds (kc = r; both panels per round) ----
    f32x4 acc2[2][2];
#pragma unroll
    for (int p = 0; p < 2; ++p)
#pragma unroll
      for (int u = 0; u < 2; ++u) acc2[p][u] = f32x4{0.f, 0.f, 0.f, 0.f};
    for (int r = 0; r < 4; ++r, ++s) {
      const u16* wcur = wtb + (s % 3) * 16384;
      __builtin_amdgcn_s_setprio(1);
#pragma unroll
      for (int kk = 0; kk < 2; ++kk) {
        bf16x8 a0 = AREAD(0, r * 64, kk);
        bf16x8 a1 = AREAD(1, r * 64, kk);
#pragma unroll
        for (int h = 0; h < 2; ++h) {
          bf16x8 b = BREAD(wcur + h * 8192, kk);
          acc2[0][h] = mfma16(a0, b, acc2[0][h]);
          acc2[1][h] = mfma16(a1, b, acc2[1][h]);
        }
      }
      __builtin_amdgcn_s_setprio(0);
      ROUND_TAIL(s);
    }
    // write av into xt
#pragma unroll
    for (int p = 0; p < 2; ++p)
#pragma unroll
      for (int h = 0; h < 2; ++h) {
        const int col = h * 128 + nloc;
        const float bb = vba[v * 256 + col];
#pragma unroll
        for (int j = 0; j < 4; ++j) {
          const int row = p * 16 + q * 4 + j;
          float vv = acc2[p][h][j] + bb;
          vv = vv > 0.f ? vv : expm1f(vv);
          xt[(row * 256 + col) ^ ((row & 7) << 3)] = f2b(vv);
        }
      }
    __syncthreads();

    // ---- m2: iv = av @ WiT + bi: 4 rounds ----
#pragma unroll
    for (int p = 0; p < 2; ++p)
#pragma unroll
      for (int u = 0; u < 2; ++u) acc2[p][u] = f32x4{0.f, 0.f, 0.f, 0.f};
    for (int r = 0; r < 4; ++r, ++s) {
      const u16* wcur = wtb + (s % 3) * 16384;
      __builtin_amdgcn_s_setprio(1);
#pragma unroll
      for (int kk = 0; kk < 2; ++kk) {
        bf16x8 a0 = AREAD(0, r * 64, kk);
        bf16x8 a1 = AREAD(1, r * 64, kk);
#pragma unroll
        for (int h = 0; h < 2; ++h) {
          bf16x8 b = BREAD(wcur + h * 8192, kk);
          acc2[0][h] = mfma16(a0, b, acc2[0][h]);
          acc2[1][h] = mfma16(a1, b, acc2[1][h]);
        }
      }
      __builtin_amdgcn_s_setprio(0);
      ROUND_TAIL(s);
    }
    // write iv into xt
#pragma unroll
    for (int p = 0; p < 2; ++p)
#pragma unroll
      for (int h = 0; h < 2; ++h) {
        const int col = h * 128 + nloc;
        const float bb = vbi[v * 256 + col];
#pragma unroll
        for (int j = 0; j < 4; ++j) {
          const int row = p * 16 + q * 4 + j;
          xt[(row * 256 + col) ^ ((row & 7) << 3)] = f2b(acc2[p][h][j] + bb);
        }
      }
    __syncthreads();

    // ---- m3: gv = iv @ WgluT: 8 rounds (kc = r>>1; quarter-pair (r&1)*2 + hq) ----
    f32x4 acc3[2][4];
#pragma unroll
    for (int p = 0; p < 2; ++p)
#pragma unroll
      for (int u = 0; u < 4; ++u) acc3[p][u] = f32x4{0.f, 0.f, 0.f, 0.f};
    for (int r = 0; r < 8; ++r, ++s) {
      const u16* wcur = wtb + (s % 3) * 16384;
      const int kc = r >> 1, qp = (r & 1) * 2;
      __builtin_amdgcn_s_setprio(1);
#pragma unroll
      for (int kk = 0; kk < 2; ++kk) {
        bf16x8 a0 = AREAD(0, kc * 64, kk);
        bf16x8 a1 = AREAD(1, kc * 64, kk);
#pragma unroll
        for (int hq = 0; hq < 2; ++hq) {
          bf16x8 b = BREAD(wcur + hq * 8192, kk);
          acc3[0][qp + hq] = mfma16(a0, b, acc3[0][qp + hq]);
          acc3[1][qp + hq] = mfma16(a1, b, acc3[1][qp + hq]);
        }
      }
      __builtin_amdgcn_s_setprio(0);
      ROUND_TAIL(s);
    }

    // ---- epilogue: GLU + residual (NT) + LN + weighted accumulate ----
    float rs[2][4], rss[2][4];
#pragma unroll
    for (int p = 0; p < 2; ++p)
#pragma unroll
      for (int j = 0; j < 4; ++j) { rs[p][j] = 0.f; rss[p][j] = 0.f; }
#pragma unroll
    for (int p = 0; p < 2; ++p)
#pragma unroll
      for (int u = 0; u < 2; ++u) {
        const int col = u * 128 + nloc;
        const float b1 = vbglu[v * 512 + col];
        const float b2 = vbglu[v * 512 + 256 + col];
#pragma unroll
        for (int j = 0; j < 4; ++j) {
          const int row = p * 16 + q * 4 + j;
          const float g1 = acc3[p][u][j] + b1;
          const float g2 = acc3[p][u + 2][j] + b2;
          const float glu = g1 / (1.f + __expf(-g2));
          const float resid = __builtin_nontemporal_load(
              &x[(size_t)(n0 + row) * 4096 + (size_t)v * 256 + col]);
          const float rr = glu + resid;
          acc3[p][u][j] = rr;
          rs[p][j] += rr; rss[p][j] += rr * rr;
        }
      }
#pragma unroll
    for (int p = 0; p < 2; ++p)
#pragma unroll
      for (int j = 0; j < 4; ++j)
#pragma unroll
        for (int d = 1; d < 16; d <<= 1) {
          rs[p][j]  += __shfl_xor(rs[p][j], d, 64);
          rss[p][j] += __shfl_xor(rss[p][j], d, 64);
        }
    if (c == 0) {
#pragma unroll
      for (int p = 0; p < 2; ++p)
#pragma unroll
        for (int j = 0; j < 4; ++j) {
          const int row = p * 16 + q * 4 + j;
          red[row * 16 + w * 2]     = rs[p][j];
          red[row * 16 + w * 2 + 1] = rss[p][j];
        }
    }
    __syncthreads();
    if (tid < 32) {
      float ms = 0.f, vs = 0.f;
#pragma unroll
      for (int ww = 0; ww < 8; ++ww) { ms += red[tid * 16 + ww * 2]; vs += red[tid * 16 + ww * 2 + 1]; }
      const float mm = ms * (1.f / 256.f);
      muinv[tid * 2]     = mm;
      muinv[tid * 2 + 1] = rsqrtf(vs * (1.f / 256.f) - mm * mm + 1e-5f);
    }
    __syncthreads();
#pragma unroll
    for (int p = 0; p < 2; ++p) {
#pragma unroll
      for (int j = 0; j < 4; ++j) {
        const int row = p * 16 + q * 4 + j;
        const float mu = muinv[row * 2], inv = muinv[row * 2 + 1];
        const float wv = sw[(size_t)(n0 + row) * 16 + v];
#pragma unroll
        for (int u = 0; u < 2; ++u) {
          const int col = u * 128 + nloc;
          const float tv = (acc3[p][u][j] - mu) * inv * vlng[v * 256 + col] + vlnb[v * 256 + col];
          outacc[p][u][j] += tv * wv;
        }
      }
    }
    __syncthreads();  // muinv/red reads done before next var reuses LDS
    if (vi < 3) {
      XSTAGE(v + 1);
      __syncthreads();  // xt(x) visible; ring slots stay resident
    }
  }

  // plain stores to this var-group's private partial buffer
  float* const dst = outp + (size_t)blockIdx.x * 2097152;
#pragma unroll
  for (int p = 0; p < 2; ++p)
#pragma unroll
    for (int u = 0; u < 2; ++u) {
      const int col = u * 128 + nloc;
#pragma unroll
      for (int j = 0; j < 4; ++j) {
        const int row = p * 16 + q * 4 + j;
        dst[(size_t)(n0 + row) * 256 + col] = outacc[p][u][j];
      }
    }
}

extern "C" void kernel_launch(void* const* d_in, const int* in_sizes, int n_in,
                              void* d_out, int out_size, void* d_ws, size_t ws_size,
                              hipStream_t stream) {
  const float* x     = (const float*)d_in[0];
  const float* ctx   = (const float*)d_in[1];
  const float* jWa   = (const float*)d_in[2];
  const float* jba   = (const float*)d_in[3];
  const float* jWc   = (const float*)d_in[4];
  const float* jWi   = (const float*)d_in[5];
  const float* jbi   = (const float*)d_in[6];
  const float* jWglu = (const float*)d_in[7];
  const float* jbglu = (const float*)d_in[8];
  const float* jWskip= (const float*)d_in[9];
  const float* jbskip= (const float*)d_in[10];
  const float* jlng  = (const float*)d_in[11];
  const float* jlnb  = (const float*)d_in[12];
  const float* vWa   = (const float*)d_in[13];
  const float* vba   = (const float*)d_in[14];
  const float* vWi   = (const float*)d_in[15];
  const float* vbi   = (const float*)d_in[16];
  const float* vWglu = (const float*)d_in[17];
  const float* vbglu = (const float*)d_in[18];
  const float* vlng  = (const float*)d_in[19];
  const float* vlnb  = (const float*)d_in[20];
  float* out = (float*)d_out;

  char* ws = (char*)d_ws;
  size_t off = 0;
  auto alloc = [&](size_t bytes) { void* p = ws + off; off += (bytes + 255) & ~(size_t)255; return p; };
  u16* bt1     = (u16*)alloc((size_t)272 * 4352 * 2);
  u16* wiT     = (u16*)alloc((size_t)256 * 256 * 2);
  u16* wgluT   = (u16*)alloc((size_t)32 * 256 * 2);
  u16* varw    = (u16*)alloc((size_t)16 * 262144 * 2);   // 16 vars x 32 tiles x 16KB
  u16* a_bf    = (u16*)alloc((size_t)8192 * 256 * 2);
  u16* i_bf    = (u16*)alloc((size_t)8192 * 256 * 2);
  float* skipf = (float*)alloc((size_t)8192 * 16 * 4);
  float* outp  = (float*)alloc((size_t)4 * 8192 * 256 * 4); // 32 MB partials

  hipMemsetAsync(bt1, 0, (size_t)272 * 4352 * 2, stream);

  dim3 blk(256);
  transpose_cast<<<dim3(8, 128, 1),  blk, 0, stream>>>(jWa,   bt1,              4096, 256, 4352, 0, 0);
  transpose_cast<<<dim3(8, 8, 1),    blk, 0, stream>>>(jWc,   bt1 + 4096,       256,  256, 4352, 0, 0);
  transpose_cast<<<dim3(1, 128, 1),  blk, 0, stream>>>(jWskip,bt1 + 256 * 4352, 4096, 16,  4352, 0, 0);
  transpose_cast<<<dim3(8, 8, 1),    blk, 0, stream>>>(jWi,   wiT,   256, 256, 256, 0, 0);
  transpose_cast<<<dim3(1, 8, 1),    blk, 0, stream>>>(jWglu, wgluT, 256, 32,  256, 0, 0);
  var_prep16<<<dim3(16, 8),  blk, 0, stream>>>(vWa,   varw, 256, 0);
  var_prep16<<<dim3(16, 8),  blk, 0, stream>>>(vWi,   varw, 256, 8);
  var_prep16<<<dim3(16, 16), blk, 0, stream>>>(vWglu, varw, 512, 16);

  gemm1<<<dim3(256), blk, 0, stream>>>(x, ctx, bt1, jba, jbskip, a_bf, skipf);
  gemm_i<<<dim3(256), blk, 0, stream>>>(a_bf, wiT, jbi, i_bf);
  joint_tail<<<dim3(2048), blk, 0, stream>>>(i_bf, wgluT, jbglu, skipf, jlng, jlnb,
                                             out + (size_t)8192 * 256);

  hipFuncSetAttribute((const void*)var_chain, hipFuncAttributeMaxDynamicSharedMemorySize, 116992);
  var_chain<<<dim3(4, 256), dim3(512), 116992, stream>>>(x, varw, vba, vbi, vbglu,
                                                         vlng, vlnb,
                                                         out + (size_t)8192 * 256, outp);
  reduce4<<<dim3(2048), blk, 0, stream>>>(outp, out);
}